// Round 13
// baseline (373.336 us; speedup 1.0000x reference)
//
#include <hip/hip_runtime.h>

#define N_NODES 50000
#define N_EDGES 600000
#define D 128
#define SCAN_BLOCKS ((N_NODES + 255) / 256)   // 196
#define PAD 8
#define PACK_CAP 950272                        // >= 600000+7*50000+8, 16B-aligned
#define SENTINEL 50000u                        // -> zero x-row, emb row 0
#define FB 1024                                // fused grid: 4 blocks/CU x 256 CUs
#define FT (FB * 256)

typedef __attribute__((ext_vector_type(8))) short short8v;
typedef __attribute__((ext_vector_type(4))) float f32x4;

__device__ __forceinline__ unsigned short f2bf(float v) {
    unsigned u = __builtin_bit_cast(unsigned, v);
    u += 0x7FFFu + ((u >> 16) & 1u);          // round-to-nearest-even
    return (unsigned short)(u >> 16);
}
__device__ __forceinline__ float bf2f(unsigned short h) {
    unsigned u = ((unsigned)h) << 16;
    return __builtin_bit_cast(float, u);
}

// ===== init: zero counts + barrier slots, sentinel prefill, zero x-row ======
__global__ __launch_bounds__(256) void init_kernel(
    int* __restrict__ counts, unsigned* __restrict__ packed,
    unsigned* __restrict__ bars, unsigned short* __restrict__ xh)
{
    int gtid = blockIdx.x * 256 + threadIdx.x;
    int NT = gridDim.x * 256;
    for (int i = gtid; i < N_NODES; i += NT) counts[i] = 0;
    uint4 s = make_uint4(SENTINEL, SENTINEL, SENTINEL, SENTINEL);
    for (int i = gtid; i < PACK_CAP / 4; i += NT)
        *(uint4*)(packed + (size_t)i * 4) = s;
    if (gtid < 4) bars[gtid] = 0;
    if (gtid >= 64 && gtid < 80) {
        short8v z = (short8v){0,0,0,0,0,0,0,0};
        *(short8v*)(xh + (size_t)N_NODES * D + (gtid - 64) * 8) = z;
    }
}

// ============== fused prep + CSR build (1024 blocks, 3 grid barriers) =======
__device__ __forceinline__ void grid_bar(unsigned* __restrict__ bars, int idx) {
    __syncthreads();
    if (threadIdx.x == 0) {
        __threadfence();
        atomicAdd(&bars[idx], 1u);
        while (atomicAdd(&bars[idx], 0u) < (unsigned)FB)
            __builtin_amdgcn_s_sleep(2);
        __threadfence();
    }
    __syncthreads();
}

__global__ __launch_bounds__(256, 4) void csr_prep_fused(
    const float* __restrict__ Wl, const float* __restrict__ Wr,
    unsigned short* __restrict__ Bh, unsigned short* __restrict__ Bl,
    const float* __restrict__ x, unsigned short* __restrict__ xh,
    const int* __restrict__ ei, const int* __restrict__ ew,
    int* __restrict__ counts, int* __restrict__ rank,
    int* __restrict__ blockSums, int* __restrict__ offs,
    unsigned* __restrict__ packed, unsigned* __restrict__ bars)
{
    __shared__ int sh[256];
    __shared__ int wsum[4];
    const int t = threadIdx.x;
    const int gtid = blockIdx.x * 256 + t;

    // --- Phase A1: W hi/lo split (B^T layout == original W layout)
    for (int i = gtid; i < 128 * 256; i += FT) {
        int n = i >> 8;
        int k = i & 255;
        float w = (k < 128) ? Wl[n * 128 + k] : Wr[n * 128 + (k - 128)];
        unsigned short h = f2bf(w);
        Bh[i] = h;
        Bl[i] = f2bf(w - bf2f(h));
    }
    // --- Phase A2: x -> bf16 (8 floats/thread/iter)
    for (int i = gtid; i < N_NODES * D / 8; i += FT) {
        const float4* p = (const float4*)(x + (size_t)i * 8);
        float4 a = p[0], b = p[1];
        short8v o;
        o[0] = (short)f2bf(a.x); o[1] = (short)f2bf(a.y);
        o[2] = (short)f2bf(a.z); o[3] = (short)f2bf(a.w);
        o[4] = (short)f2bf(b.x); o[5] = (short)f2bf(b.y);
        o[6] = (short)f2bf(b.z); o[7] = (short)f2bf(b.w);
        *(short8v*)(xh + (size_t)i * 8) = o;
    }
    // --- Phase A3: histogram + per-edge rank
    for (int e = gtid; e < N_EDGES; e += FT)
        rank[e] = atomicAdd(&counts[ei[N_EDGES + e]], 1);
    grid_bar(bars, 0);

    // --- Phase B: per-block sums of PADDED counts (first 196 blocks carry data)
    {
        int v = (gtid < N_NODES) ? ((counts[gtid] + PAD - 1) & ~(PAD - 1)) : 0;
        int r = v;
#pragma unroll
        for (int off = 32; off > 0; off >>= 1) r += __shfl_down(r, off, 64);
        int lane = t & 63, wid = t >> 6;
        if (lane == 0) wsum[wid] = r;
        __syncthreads();
        if (t == 0 && blockIdx.x < SCAN_BLOCKS)
            blockSums[blockIdx.x] = wsum[0] + wsum[1] + wsum[2] + wsum[3];
    }
    grid_bar(bars, 1);

    // --- Phase C: scan (every block scans the 196 block sums, then local)
    {
        int bs = (t < SCAN_BLOCKS) ? blockSums[t] : 0;
        sh[t] = bs;
        __syncthreads();
        for (int off = 1; off < 256; off <<= 1) {
            int u = (t >= off) ? sh[t - off] : 0;
            __syncthreads();
            sh[t] += u;
            __syncthreads();
        }
        int blockOff = (blockIdx.x > 0 && blockIdx.x < SCAN_BLOCKS)
                           ? sh[blockIdx.x - 1] : 0;
        if (blockIdx.x == 0 && t == 0) offs[N_NODES] = sh[SCAN_BLOCKS - 1];

        int v = (gtid < N_NODES) ? ((counts[gtid] + PAD - 1) & ~(PAD - 1)) : 0;
        int lane = t & 63, wid = t >> 6;
        int s = v;
#pragma unroll
        for (int off = 1; off < 64; off <<= 1) {
            int u = __shfl_up(s, off, 64);
            if (lane >= off) s += u;
        }
        __syncthreads();
        if (lane == 63) wsum[wid] = s;
        __syncthreads();
        int wadd = 0;
        for (int w = 0; w < wid; w++) wadd += wsum[w];
        if (gtid < N_NODES)
            offs[gtid] = blockOff + s + wadd - v;
    }
    grid_bar(bars, 2);

    // --- Phase D: pack (pos = offs[dst] + rank[e]; RMW-free)
    for (int e = gtid; e < N_EDGES; e += FT) {
        int dst = ei[N_EDGES + e];
        packed[offs[dst] + rank[e]] = (unsigned)ei[e] | ((unsigned)ew[e] << 16);
    }
}

// ============ aggregate: 1 node per FULL wave, 2 cols/lane ==================
// Segments padded to x8 with sentinels -> exact trip count, no masks.
// beg/end forced scalar -> packed batch loads go to the scalar pipe.
__global__ __launch_bounds__(256) void aggregate_kernel(
    const unsigned short* __restrict__ xh,
    const float* __restrict__ emb,
    const int* __restrict__ offs,
    const unsigned* __restrict__ packed,
    unsigned short* __restrict__ ph, unsigned short* __restrict__ pl)
{
    __shared__ float emb_s[10][D];
    for (int i = threadIdx.x; i < 10 * D; i += 256)
        emb_s[i >> 7][i & 127] = emb[i];
    __syncthreads();

    int node = blockIdx.x * 4 + (threadIdx.x >> 6);
    if (node >= N_NODES) return;
    int c = (threadIdx.x & 63) * 2;

    int beg = __builtin_amdgcn_readfirstlane(offs[node]);
    int end = __builtin_amdgcn_readfirstlane(offs[node + 1]);
    float2 acc = make_float2(0.f, 0.f);

    for (int i = beg; i < end; i += 8) {
        uint4 a0 = *(const uint4*)(packed + i);
        uint4 a1 = *(const uint4*)(packed + i + 4);
        unsigned pk[8] = {a0.x, a0.y, a0.z, a0.w, a1.x, a1.y, a1.z, a1.w};
        unsigned xr[8];
#pragma unroll
        for (int q = 0; q < 8; q++)
            xr[q] = *(const unsigned*)(xh + (size_t)(pk[q] & 0xFFFFu) * D + c);
#pragma unroll
        for (int q = 0; q < 8; q++) {
            float2 er = *(const float2*)&emb_s[pk[q] >> 16][c];
            acc.x += er.x * bf2f((unsigned short)(xr[q] & 0xFFFFu));
            acc.y += er.y * bf2f((unsigned short)(xr[q] >> 16));
        }
    }
    unsigned short h0 = f2bf(acc.x), h1 = f2bf(acc.y);
    unsigned short l0 = f2bf(acc.x - bf2f(h0)), l1 = f2bf(acc.y - bf2f(h1));
    *(unsigned*)(ph + (size_t)node * D + c) = (unsigned)h0 | ((unsigned)h1 << 16);
    *(unsigned*)(pl + (size_t)node * D + c) = (unsigned)l0 | ((unsigned)l1 << 16);
}

// ================= MFMA GEMM ================================================
// out = [x | prop] @ [Wl^T ; Wr^T] + (b_l + b_r),   K = 256, N = 128
__global__ __launch_bounds__(256) void mfma_gemm(
    const float* __restrict__ x,
    const unsigned short* __restrict__ ph, const unsigned short* __restrict__ pl,
    float*       __restrict__ out,
    const unsigned short* __restrict__ Bh,  // [128][256]
    const unsigned short* __restrict__ Bl,
    const float* __restrict__ bl_,
    const float* __restrict__ br_)
{
    __shared__ unsigned short Ah_s[128 * 40];
    __shared__ unsigned short Al_s[128 * 40];
    __shared__ unsigned short Bh_s[128 * 40];
    __shared__ unsigned short Bl_s[128 * 40];

    const int tid  = threadIdx.x;
    const int lane = tid & 63;
    const int wave = tid >> 6;
    const int row0 = blockIdx.x * 128;

    const int wr0 = (wave >> 1) * 64;
    const int wc0 = (wave & 1) * 64;
    const int lr  = lane & 15;
    const int lk8 = (lane >> 4) * 8;

    const int srow  = tid >> 1;
    const int skoff = (tid & 1) * 16;

    f32x4 acc[4][4];
#pragma unroll
    for (int i = 0; i < 4; i++)
#pragma unroll
        for (int j = 0; j < 4; j++)
            acc[i][j] = (f32x4){0.f, 0.f, 0.f, 0.f};

    for (int kc = 0; kc < 8; ++kc) {
        const int kbase = kc * 32;
        const int grow = row0 + srow;
        if (kbase < 128) {
            float v[16];
            if (grow < N_NODES) {
                const float4* p = (const float4*)(x + (size_t)grow * D + kbase + skoff);
#pragma unroll
                for (int q = 0; q < 4; q++) {
                    float4 f = p[q];
                    v[q*4+0] = f.x; v[q*4+1] = f.y; v[q*4+2] = f.z; v[q*4+3] = f.w;
                }
            } else {
#pragma unroll
                for (int q = 0; q < 16; q++) v[q] = 0.f;
            }
            short8v h0, h1, l0, l1;
#pragma unroll
            for (int q = 0; q < 8; q++) {
                unsigned short h = f2bf(v[q]);
                h0[q] = (short)h;
                l0[q] = (short)f2bf(v[q] - bf2f(h));
            }
#pragma unroll
            for (int q = 0; q < 8; q++) {
                unsigned short h = f2bf(v[q + 8]);
                h1[q] = (short)h;
                l1[q] = (short)f2bf(v[q + 8] - bf2f(h));
            }
            *(short8v*)(Ah_s + srow * 40 + skoff)     = h0;
            *(short8v*)(Ah_s + srow * 40 + skoff + 8) = h1;
            *(short8v*)(Al_s + srow * 40 + skoff)     = l0;
            *(short8v*)(Al_s + srow * 40 + skoff + 8) = l1;
        } else {
            const size_t off = (size_t)grow * D + (kbase & 127) + skoff;
            short8v h0, h1, l0, l1;
            if (grow < N_NODES) {
                h0 = *(const short8v*)(ph + off);
                h1 = *(const short8v*)(ph + off + 8);
                l0 = *(const short8v*)(pl + off);
                l1 = *(const short8v*)(pl + off + 8);
            } else {
                h0 = h1 = l0 = l1 = (short8v){0,0,0,0,0,0,0,0};
            }
            *(short8v*)(Ah_s + srow * 40 + skoff)     = h0;
            *(short8v*)(Ah_s + srow * 40 + skoff + 8) = h1;
            *(short8v*)(Al_s + srow * 40 + skoff)     = l0;
            *(short8v*)(Al_s + srow * 40 + skoff + 8) = l1;
        }
        {
            const size_t boff = (size_t)srow * 256 + kbase + skoff;
            short8v bh0 = *(const short8v*)(Bh + boff);
            short8v bh1 = *(const short8v*)(Bh + boff + 8);
            short8v bl0 = *(const short8v*)(Bl + boff);
            short8v bl1 = *(const short8v*)(Bl + boff + 8);
            *(short8v*)(Bh_s + srow * 40 + skoff)     = bh0;
            *(short8v*)(Bh_s + srow * 40 + skoff + 8) = bh1;
            *(short8v*)(Bl_s + srow * 40 + skoff)     = bl0;
            *(short8v*)(Bl_s + srow * 40 + skoff + 8) = bl1;
        }
        __syncthreads();
        short8v afh[4], afl[4];
#pragma unroll
        for (int rt = 0; rt < 4; rt++) {
            int ar = wr0 + rt * 16 + lr;
            afh[rt] = *(const short8v*)(Ah_s + ar * 40 + lk8);
            afl[rt] = *(const short8v*)(Al_s + ar * 40 + lk8);
        }
#pragma unroll
        for (int ct = 0; ct < 4; ct++) {
            int bc = wc0 + ct * 16 + lr;
            short8v bfh = *(const short8v*)(Bh_s + bc * 40 + lk8);
            short8v bfl = *(const short8v*)(Bl_s + bc * 40 + lk8);
#pragma unroll
            for (int rt = 0; rt < 4; rt++)
                acc[rt][ct] = __builtin_amdgcn_mfma_f32_16x16x32_bf16(afh[rt], bfh, acc[rt][ct], 0, 0, 0);
#pragma unroll
            for (int rt = 0; rt < 4; rt++)
                acc[rt][ct] = __builtin_amdgcn_mfma_f32_16x16x32_bf16(afl[rt], bfh, acc[rt][ct], 0, 0, 0);
#pragma unroll
            for (int rt = 0; rt < 4; rt++)
                acc[rt][ct] = __builtin_amdgcn_mfma_f32_16x16x32_bf16(afh[rt], bfl, acc[rt][ct], 0, 0, 0);
        }
        __syncthreads();
    }

    const int drow = (lane >> 4) * 4;
#pragma unroll
    for (int ct = 0; ct < 4; ct++) {
        int col = wc0 + ct * 16 + lr;
        float bias = bl_[col] + br_[col];
#pragma unroll
        for (int rt = 0; rt < 4; rt++) {
#pragma unroll
            for (int r = 0; r < 4; r++) {
                int grow = row0 + wr0 + rt * 16 + drow + r;
                if (grow < N_NODES)
                    out[(size_t)grow * D + col] = acc[rt][ct][r] + bias;
            }
        }
    }
}

// ===================== fallback path (atomic, f32) ==========================

__global__ void zero_kernel(float4* __restrict__ out, int n4) {
    int i = blockIdx.x * blockDim.x + threadIdx.x;
    int stride = gridDim.x * blockDim.x;
    for (; i < n4; i += stride) out[i] = make_float4(0.f, 0.f, 0.f, 0.f);
}

__global__ __launch_bounds__(256) void wprep_kernel(
    const float* __restrict__ Wl, const float* __restrict__ Wr,
    unsigned short* __restrict__ Bh, unsigned short* __restrict__ Bl)
{
    int t = blockIdx.x * 256 + threadIdx.x;
    if (t >= 128 * 256) return;
    int n = t >> 8;
    int k = t & 255;
    float w = (k < 128) ? Wl[n * 128 + k] : Wr[n * 128 + (k - 128)];
    unsigned short h = f2bf(w);
    Bh[t] = h;
    Bl[t] = f2bf(w - bf2f(h));
}

__global__ __launch_bounds__(256) void scatter_kernel(
    const float* __restrict__ x,
    const float* __restrict__ emb,
    const int*   __restrict__ ei,
    const int*   __restrict__ ew,
    float*       __restrict__ prop)
{
    int gid = blockIdx.x * blockDim.x + threadIdx.x;
    int e = gid >> 5;
    if (e >= N_EDGES) return;
    int d4 = (gid & 31) * 4;
    int src = ei[e];
    int dst = ei[N_EDGES + e];
    int w   = ew[e];
    float4 ev = *(const float4*)(emb + (size_t)w * D + d4);
    float4 xv = *(const float4*)(x + (size_t)src * D + d4);
    float* p = prop + (size_t)dst * D + d4;
    atomicAdd(p + 0, ev.x * xv.x);
    atomicAdd(p + 1, ev.y * xv.y);
    atomicAdd(p + 2, ev.z * xv.z);
    atomicAdd(p + 3, ev.w * xv.w);
}

__global__ __launch_bounds__(256) void mfma_gemm_fb(
    const float* __restrict__ x,
    float*       __restrict__ out,
    const unsigned short* __restrict__ Bh,
    const unsigned short* __restrict__ Bl,
    const float* __restrict__ bl_,
    const float* __restrict__ br_)
{
    __shared__ unsigned short Ah_s[128 * 40];
    __shared__ unsigned short Al_s[128 * 40];
    __shared__ unsigned short Bh_s[128 * 40];
    __shared__ unsigned short Bl_s[128 * 40];

    const int tid  = threadIdx.x;
    const int lane = tid & 63;
    const int wave = tid >> 6;
    const int row0 = blockIdx.x * 128;
    const int wr0 = (wave >> 1) * 64;
    const int wc0 = (wave & 1) * 64;
    const int lr  = lane & 15;
    const int lk8 = (lane >> 4) * 8;
    const int srow  = tid >> 1;
    const int skoff = (tid & 1) * 16;

    f32x4 acc[4][4];
#pragma unroll
    for (int i = 0; i < 4; i++)
#pragma unroll
        for (int j = 0; j < 4; j++)
            acc[i][j] = (f32x4){0.f, 0.f, 0.f, 0.f};

    for (int kc = 0; kc < 8; ++kc) {
        const int kbase = kc * 32;
        {
            const float* Asrc = (kbase < 128) ? x : out;
            const int acol = (kbase & 127) + skoff;
            const int grow = row0 + srow;
            float v[16];
            if (grow < N_NODES) {
                const float4* p = (const float4*)(Asrc + (size_t)grow * D + acol);
#pragma unroll
                for (int q = 0; q < 4; q++) {
                    float4 f = p[q];
                    v[q*4+0] = f.x; v[q*4+1] = f.y; v[q*4+2] = f.z; v[q*4+3] = f.w;
                }
            } else {
#pragma unroll
                for (int q = 0; q < 16; q++) v[q] = 0.f;
            }
            short8v h0, h1, l0, l1;
#pragma unroll
            for (int q = 0; q < 8; q++) {
                unsigned short h = f2bf(v[q]);
                h0[q] = (short)h;
                l0[q] = (short)f2bf(v[q] - bf2f(h));
            }
#pragma unroll
            for (int q = 0; q < 8; q++) {
                unsigned short h = f2bf(v[q + 8]);
                h1[q] = (short)h;
                l1[q] = (short)f2bf(v[q + 8] - bf2f(h));
            }
            *(short8v*)(Ah_s + srow * 40 + skoff)     = h0;
            *(short8v*)(Ah_s + srow * 40 + skoff + 8) = h1;
            *(short8v*)(Al_s + srow * 40 + skoff)     = l0;
            *(short8v*)(Al_s + srow * 40 + skoff + 8) = l1;
        }
        {
            const size_t boff = (size_t)srow * 256 + kbase + skoff;
            *(short8v*)(Bh_s + srow * 40 + skoff)     = *(const short8v*)(Bh + boff);
            *(short8v*)(Bh_s + srow * 40 + skoff + 8) = *(const short8v*)(Bh + boff + 8);
            *(short8v*)(Bl_s + srow * 40 + skoff)     = *(const short8v*)(Bl + boff);
            *(short8v*)(Bl_s + srow * 40 + skoff + 8) = *(const short8v*)(Bl + boff + 8);
        }
        __syncthreads();
        short8v afh[4], afl[4];
#pragma unroll
        for (int rt = 0; rt < 4; rt++) {
            int ar = wr0 + rt * 16 + lr;
            afh[rt] = *(const short8v*)(Ah_s + ar * 40 + lk8);
            afl[rt] = *(const short8v*)(Al_s + ar * 40 + lk8);
        }
#pragma unroll
        for (int ct = 0; ct < 4; ct++) {
            int bc = wc0 + ct * 16 + lr;
            short8v bfh = *(const short8v*)(Bh_s + bc * 40 + lk8);
            short8v bfl = *(const short8v*)(Bl_s + bc * 40 + lk8);
#pragma unroll
            for (int rt = 0; rt < 4; rt++)
                acc[rt][ct] = __builtin_amdgcn_mfma_f32_16x16x32_bf16(afh[rt], bfh, acc[rt][ct], 0, 0, 0);
#pragma unroll
            for (int rt = 0; rt < 4; rt++)
                acc[rt][ct] = __builtin_amdgcn_mfma_f32_16x16x32_bf16(afl[rt], bfh, acc[rt][ct], 0, 0, 0);
#pragma unroll
            for (int rt = 0; rt < 4; rt++)
                acc[rt][ct] = __builtin_amdgcn_mfma_f32_16x16x32_bf16(afh[rt], bfl, acc[rt][ct], 0, 0, 0);
        }
        __syncthreads();
    }

    const int drow = (lane >> 4) * 4;
#pragma unroll
    for (int ct = 0; ct < 4; ct++) {
        int col = wc0 + ct * 16 + lr;
        float bias = bl_[col] + br_[col];
#pragma unroll
        for (int rt = 0; rt < 4; rt++) {
#pragma unroll
            for (int r = 0; r < 4; r++) {
                int grow = row0 + wr0 + rt * 16 + drow + r;
                if (grow < N_NODES)
                    out[(size_t)grow * D + col] = acc[rt][ct][r] + bias;
            }
        }
    }
}

// ============================================================================
extern "C" void kernel_launch(void* const* d_in, const int* in_sizes, int n_in,
                              void* d_out, int out_size, void* d_ws, size_t ws_size,
                              hipStream_t stream) {
    const float* x    = (const float*)d_in[0];
    const float* emb  = (const float*)d_in[1];
    const float* W_l  = (const float*)d_in[2];
    const float* b_l  = (const float*)d_in[3];
    const float* W_r  = (const float*)d_in[4];
    const float* b_r  = (const float*)d_in[5];
    const int*   ei   = (const int*)d_in[6];
    const int*   ew   = (const int*)d_in[7];

    float* out = (float*)d_out;

    char* wsp = (char*)d_ws;
    unsigned short* Bh  = (unsigned short*)wsp; wsp += 128 * 256 * sizeof(unsigned short);
    unsigned short* Bl  = (unsigned short*)wsp; wsp += 128 * 256 * sizeof(unsigned short);
    unsigned short* xh  = (unsigned short*)wsp; wsp += (size_t)(N_NODES + 1) * D * sizeof(unsigned short);
    unsigned short* ph  = (unsigned short*)wsp; wsp += (size_t)N_NODES * D * sizeof(unsigned short);
    unsigned short* pl  = (unsigned short*)wsp; wsp += (size_t)N_NODES * D * sizeof(unsigned short);
    int*      counts    = (int*)wsp;     wsp += N_NODES * sizeof(int);
    int*      offs      = (int*)wsp;     wsp += (N_NODES + 1) * sizeof(int);
    int*      rank      = (int*)wsp;     wsp += N_EDGES * sizeof(int);
    int*      blockSums = (int*)wsp;     wsp += SCAN_BLOCKS * sizeof(int);
    unsigned* bars      = (unsigned*)wsp; wsp += 4 * sizeof(unsigned);
    unsigned* packed    = (unsigned*)wsp; wsp += (size_t)PACK_CAP * sizeof(unsigned);
    size_t needed = (size_t)(wsp - (char*)d_ws);

    if (ws_size >= needed) {
        init_kernel<<<512, 256, 0, stream>>>(counts, packed, bars, xh);
        csr_prep_fused<<<FB, 256, 0, stream>>>(
            W_l, W_r, Bh, Bl, x, xh, ei, ew,
            counts, rank, blockSums, offs, packed, bars);
        aggregate_kernel<<<(N_NODES + 3) / 4, 256, 0, stream>>>(
            xh, emb, offs, packed, ph, pl);
        mfma_gemm<<<(N_NODES + 127) / 128, 256, 0, stream>>>(
            x, ph, pl, out, Bh, Bl, b_l, b_r);
    } else {
        wprep_kernel<<<128, 256, 0, stream>>>(W_l, W_r, Bh, Bl);
        int n4 = N_NODES * D / 4;
        zero_kernel<<<(n4 + 255) / 256, 256, 0, stream>>>((float4*)out, n4);
        long long work = (long long)N_EDGES * 32;
        scatter_kernel<<<(int)((work + 255) / 256), 256, 0, stream>>>(x, emb, ei, ew, out);
        mfma_gemm_fb<<<(N_NODES + 127) / 128, 256, 0, stream>>>(x, out, Bh, Bl, b_l, b_r);
    }
}

// Round 14
// 105.392 us; speedup vs baseline: 3.5423x; 3.5423x over previous
//
#include <hip/hip_runtime.h>

#define N_NODES 50000
#define N_EDGES 600000
#define D 128
#define SCAN_BLOCKS ((N_NODES + 255) / 256)   // 196
#define PAD 8
#define PACK_CAP 950272                        // >= 600000+7*50000+8, 16B-aligned
#define PFILL_BLOCKS (PACK_CAP / 1024)         // 928
#define SENTINEL 50000u                        // -> zero x-row, emb row 0

typedef __attribute__((ext_vector_type(8))) short short8v;
typedef __attribute__((ext_vector_type(4))) float f32x4;

__device__ __forceinline__ unsigned short f2bf(float v) {
    unsigned u = __builtin_bit_cast(unsigned, v);
    u += 0x7FFFu + ((u >> 16) & 1u);          // round-to-nearest-even
    return (unsigned short)(u >> 16);
}
__device__ __forceinline__ float bf2f(unsigned short h) {
    unsigned u = ((unsigned)h) << 16;
    return __builtin_bit_cast(float, u);
}

// ==== prep: W hi/lo + x->bf16 + zero counts/cursor + sentinel prefill =======
#define XPREP_BLOCKS ((N_NODES * D / 8 + 255) / 256)   // 3125
__global__ __launch_bounds__(256) void prep_kernel(
    const float* __restrict__ Wl, const float* __restrict__ Wr,
    unsigned short* __restrict__ Bh, unsigned short* __restrict__ Bl,
    const float* __restrict__ x, unsigned short* __restrict__ xh,
    int* __restrict__ counts, unsigned* __restrict__ packed,
    unsigned* __restrict__ cursor)
{
    int bid = blockIdx.x;
    if (bid < 128) {
        int t = bid * 256 + threadIdx.x;          // 128*256 W elements
        int n = t >> 8;
        int k = t & 255;
        float w = (k < 128) ? Wl[n * 128 + k] : Wr[n * 128 + (k - 128)];
        unsigned short h = f2bf(w);
        Bh[t] = h;
        Bl[t] = f2bf(w - bf2f(h));
    } else if (bid < 128 + XPREP_BLOCKS) {
        int t = (bid - 128) * 256 + threadIdx.x;  // 8 floats per thread
        if (t < N_NODES * D / 8) {
            const float4* p = (const float4*)(x + (size_t)t * 8);
            float4 a = p[0], b = p[1];
            short8v o;
            o[0] = (short)f2bf(a.x); o[1] = (short)f2bf(a.y);
            o[2] = (short)f2bf(a.z); o[3] = (short)f2bf(a.w);
            o[4] = (short)f2bf(b.x); o[5] = (short)f2bf(b.y);
            o[6] = (short)f2bf(b.z); o[7] = (short)f2bf(b.w);
            *(short8v*)(xh + (size_t)t * 8) = o;
        }
    } else if (bid < 128 + XPREP_BLOCKS + SCAN_BLOCKS) {
        int t = (bid - 128 - XPREP_BLOCKS) * 256 + threadIdx.x;
        if (t < N_NODES) counts[t] = 0;
    } else if (bid < 128 + XPREP_BLOCKS + SCAN_BLOCKS + PFILL_BLOCKS) {
        int t = (bid - 128 - XPREP_BLOCKS - SCAN_BLOCKS) * 1024 + threadIdx.x * 4;
        uint4 s = make_uint4(SENTINEL, SENTINEL, SENTINEL, SENTINEL);
        *(uint4*)(packed + t) = s;
    } else {
        if (threadIdx.x < 16) {                   // zero x-row for sentinels
            short8v z = (short8v){0,0,0,0,0,0,0,0};
            *(short8v*)(xh + (size_t)N_NODES * D + threadIdx.x * 8) = z;
        }
        if (threadIdx.x == 32) cursor[0] = 0;     // alloc cursor
    }
}

// ============================== CSR-build path ==============================

__global__ __launch_bounds__(256) void histrank_kernel(
    const int* __restrict__ ei, int* __restrict__ counts,
    int* __restrict__ rank)
{
    int e = blockIdx.x * blockDim.x + threadIdx.x;
    if (e >= N_EDGES) return;
    rank[e] = atomicAdd(&counts[ei[N_EDGES + e]], 1);
}

// single-kernel segment allocation: block prefix-sum of padded counts + one
// global atomicAdd per block for the base. Replaces the two scan kernels.
// (Segment placement varies run-to-run; per-node content order does not.)
__global__ __launch_bounds__(256) void alloc_kernel(
    const int* __restrict__ counts,
    unsigned* __restrict__ cursor,
    int* __restrict__ offs)
{
    __shared__ int wsum[4];
    __shared__ int base_s;
    int t = threadIdx.x;
    int i = blockIdx.x * 256 + t;
    int cp = (i < N_NODES) ? ((counts[i] + PAD - 1) & ~(PAD - 1)) : 0;
    int lane = t & 63, wid = t >> 6;
    int s = cp;
#pragma unroll
    for (int off = 1; off < 64; off <<= 1) {
        int u = __shfl_up(s, off, 64);
        if (lane >= off) s += u;
    }
    if (lane == 63) wsum[wid] = s;
    __syncthreads();
    if (t == 0) {
        int total = wsum[0] + wsum[1] + wsum[2] + wsum[3];
        base_s = (int)atomicAdd(cursor, (unsigned)total);
    }
    __syncthreads();
    int wadd = 0;
    for (int w = 0; w < wid; w++) wadd += wsum[w];
    if (i < N_NODES)
        offs[i] = base_s + wadd + s - cp;
}

// pos = offs[dst] + rank[e]; no atomic in the chain; sentinel slots untouched
__global__ __launch_bounds__(256) void pack_kernel(
    const int* __restrict__ ei,
    const int* __restrict__ ew,
    const int* __restrict__ offs,
    const int* __restrict__ rank,
    unsigned* __restrict__ packed)
{
    int e = blockIdx.x * blockDim.x + threadIdx.x;
    if (e >= N_EDGES) return;
    int dst = ei[N_EDGES + e];
    int r   = rank[e];
    int pos = offs[dst] + r;
    packed[pos] = (unsigned)ei[e] | ((unsigned)ew[e] << 16);
}

// ============ aggregate: 1 node per FULL wave, 2 cols/lane ==================
// Segments padded to x8 with sentinels -> exact trip count, no masks.
// end derived from counts (offs[node+1] no longer meaningful under alloc).
__global__ __launch_bounds__(256) void aggregate_kernel(
    const unsigned short* __restrict__ xh,
    const float* __restrict__ emb,
    const int* __restrict__ offs,
    const int* __restrict__ counts,
    const unsigned* __restrict__ packed,
    unsigned short* __restrict__ ph, unsigned short* __restrict__ pl)
{
    __shared__ float emb_s[10][D];
    for (int i = threadIdx.x; i < 10 * D; i += 256)
        emb_s[i >> 7][i & 127] = emb[i];
    __syncthreads();

    int node = blockIdx.x * 4 + (threadIdx.x >> 6);
    if (node >= N_NODES) return;
    int c = (threadIdx.x & 63) * 2;

    int beg = __builtin_amdgcn_readfirstlane(offs[node]);
    int cnt = __builtin_amdgcn_readfirstlane((counts[node] + PAD - 1) & ~(PAD - 1));
    int end = beg + cnt;
    float2 acc = make_float2(0.f, 0.f);

    for (int i = beg; i < end; i += 8) {
        uint4 a0 = *(const uint4*)(packed + i);
        uint4 a1 = *(const uint4*)(packed + i + 4);
        unsigned pk[8] = {a0.x, a0.y, a0.z, a0.w, a1.x, a1.y, a1.z, a1.w};
        unsigned xr[8];
#pragma unroll
        for (int q = 0; q < 8; q++)
            xr[q] = *(const unsigned*)(xh + (size_t)(pk[q] & 0xFFFFu) * D + c);
#pragma unroll
        for (int q = 0; q < 8; q++) {
            float2 er = *(const float2*)&emb_s[pk[q] >> 16][c];
            acc.x += er.x * bf2f((unsigned short)(xr[q] & 0xFFFFu));
            acc.y += er.y * bf2f((unsigned short)(xr[q] >> 16));
        }
    }
    unsigned short h0 = f2bf(acc.x), h1 = f2bf(acc.y);
    unsigned short l0 = f2bf(acc.x - bf2f(h0)), l1 = f2bf(acc.y - bf2f(h1));
    *(unsigned*)(ph + (size_t)node * D + c) = (unsigned)h0 | ((unsigned)h1 << 16);
    *(unsigned*)(pl + (size_t)node * D + c) = (unsigned)l0 | ((unsigned)l1 << 16);
}

// ================= MFMA GEMM ================================================
// out = [x | prop] @ [Wl^T ; Wr^T] + (b_l + b_r),   K = 256, N = 128
__global__ __launch_bounds__(256) void mfma_gemm(
    const float* __restrict__ x,
    const unsigned short* __restrict__ ph, const unsigned short* __restrict__ pl,
    float*       __restrict__ out,
    const unsigned short* __restrict__ Bh,  // [128][256]
    const unsigned short* __restrict__ Bl,
    const float* __restrict__ bl_,
    const float* __restrict__ br_)
{
    __shared__ unsigned short Ah_s[128 * 40];
    __shared__ unsigned short Al_s[128 * 40];
    __shared__ unsigned short Bh_s[128 * 40];
    __shared__ unsigned short Bl_s[128 * 40];

    const int tid  = threadIdx.x;
    const int lane = tid & 63;
    const int wave = tid >> 6;
    const int row0 = blockIdx.x * 128;

    const int wr0 = (wave >> 1) * 64;
    const int wc0 = (wave & 1) * 64;
    const int lr  = lane & 15;
    const int lk8 = (lane >> 4) * 8;

    const int srow  = tid >> 1;
    const int skoff = (tid & 1) * 16;

    f32x4 acc[4][4];
#pragma unroll
    for (int i = 0; i < 4; i++)
#pragma unroll
        for (int j = 0; j < 4; j++)
            acc[i][j] = (f32x4){0.f, 0.f, 0.f, 0.f};

    for (int kc = 0; kc < 8; ++kc) {
        const int kbase = kc * 32;
        const int grow = row0 + srow;
        if (kbase < 128) {
            float v[16];
            if (grow < N_NODES) {
                const float4* p = (const float4*)(x + (size_t)grow * D + kbase + skoff);
#pragma unroll
                for (int q = 0; q < 4; q++) {
                    float4 f = p[q];
                    v[q*4+0] = f.x; v[q*4+1] = f.y; v[q*4+2] = f.z; v[q*4+3] = f.w;
                }
            } else {
#pragma unroll
                for (int q = 0; q < 16; q++) v[q] = 0.f;
            }
            short8v h0, h1, l0, l1;
#pragma unroll
            for (int q = 0; q < 8; q++) {
                unsigned short h = f2bf(v[q]);
                h0[q] = (short)h;
                l0[q] = (short)f2bf(v[q] - bf2f(h));
            }
#pragma unroll
            for (int q = 0; q < 8; q++) {
                unsigned short h = f2bf(v[q + 8]);
                h1[q] = (short)h;
                l1[q] = (short)f2bf(v[q + 8] - bf2f(h));
            }
            *(short8v*)(Ah_s + srow * 40 + skoff)     = h0;
            *(short8v*)(Ah_s + srow * 40 + skoff + 8) = h1;
            *(short8v*)(Al_s + srow * 40 + skoff)     = l0;
            *(short8v*)(Al_s + srow * 40 + skoff + 8) = l1;
        } else {
            const size_t off = (size_t)grow * D + (kbase & 127) + skoff;
            short8v h0, h1, l0, l1;
            if (grow < N_NODES) {
                h0 = *(const short8v*)(ph + off);
                h1 = *(const short8v*)(ph + off + 8);
                l0 = *(const short8v*)(pl + off);
                l1 = *(const short8v*)(pl + off + 8);
            } else {
                h0 = h1 = l0 = l1 = (short8v){0,0,0,0,0,0,0,0};
            }
            *(short8v*)(Ah_s + srow * 40 + skoff)     = h0;
            *(short8v*)(Ah_s + srow * 40 + skoff + 8) = h1;
            *(short8v*)(Al_s + srow * 40 + skoff)     = l0;
            *(short8v*)(Al_s + srow * 40 + skoff + 8) = l1;
        }
        {
            const size_t boff = (size_t)srow * 256 + kbase + skoff;
            short8v bh0 = *(const short8v*)(Bh + boff);
            short8v bh1 = *(const short8v*)(Bh + boff + 8);
            short8v bl0 = *(const short8v*)(Bl + boff);
            short8v bl1 = *(const short8v*)(Bl + boff + 8);
            *(short8v*)(Bh_s + srow * 40 + skoff)     = bh0;
            *(short8v*)(Bh_s + srow * 40 + skoff + 8) = bh1;
            *(short8v*)(Bl_s + srow * 40 + skoff)     = bl0;
            *(short8v*)(Bl_s + srow * 40 + skoff + 8) = bl1;
        }
        __syncthreads();
        short8v afh[4], afl[4];
#pragma unroll
        for (int rt = 0; rt < 4; rt++) {
            int ar = wr0 + rt * 16 + lr;
            afh[rt] = *(const short8v*)(Ah_s + ar * 40 + lk8);
            afl[rt] = *(const short8v*)(Al_s + ar * 40 + lk8);
        }
#pragma unroll
        for (int ct = 0; ct < 4; ct++) {
            int bc = wc0 + ct * 16 + lr;
            short8v bfh = *(const short8v*)(Bh_s + bc * 40 + lk8);
            short8v bfl = *(const short8v*)(Bl_s + bc * 40 + lk8);
#pragma unroll
            for (int rt = 0; rt < 4; rt++)
                acc[rt][ct] = __builtin_amdgcn_mfma_f32_16x16x32_bf16(afh[rt], bfh, acc[rt][ct], 0, 0, 0);
#pragma unroll
            for (int rt = 0; rt < 4; rt++)
                acc[rt][ct] = __builtin_amdgcn_mfma_f32_16x16x32_bf16(afl[rt], bfh, acc[rt][ct], 0, 0, 0);
#pragma unroll
            for (int rt = 0; rt < 4; rt++)
                acc[rt][ct] = __builtin_amdgcn_mfma_f32_16x16x32_bf16(afh[rt], bfl, acc[rt][ct], 0, 0, 0);
        }
        __syncthreads();
    }

    const int drow = (lane >> 4) * 4;
#pragma unroll
    for (int ct = 0; ct < 4; ct++) {
        int col = wc0 + ct * 16 + lr;
        float bias = bl_[col] + br_[col];
#pragma unroll
        for (int rt = 0; rt < 4; rt++) {
#pragma unroll
            for (int r = 0; r < 4; r++) {
                int grow = row0 + wr0 + rt * 16 + drow + r;
                if (grow < N_NODES)
                    out[(size_t)grow * D + col] = acc[rt][ct][r] + bias;
            }
        }
    }
}

// ===================== fallback path (atomic, f32) ==========================

__global__ void zero_kernel(float4* __restrict__ out, int n4) {
    int i = blockIdx.x * blockDim.x + threadIdx.x;
    int stride = gridDim.x * blockDim.x;
    for (; i < n4; i += stride) out[i] = make_float4(0.f, 0.f, 0.f, 0.f);
}

__global__ __launch_bounds__(256) void wprep_kernel(
    const float* __restrict__ Wl, const float* __restrict__ Wr,
    unsigned short* __restrict__ Bh, unsigned short* __restrict__ Bl)
{
    int t = blockIdx.x * 256 + threadIdx.x;
    if (t >= 128 * 256) return;
    int n = t >> 8;
    int k = t & 255;
    float w = (k < 128) ? Wl[n * 128 + k] : Wr[n * 128 + (k - 128)];
    unsigned short h = f2bf(w);
    Bh[t] = h;
    Bl[t] = f2bf(w - bf2f(h));
}

__global__ __launch_bounds__(256) void scatter_kernel(
    const float* __restrict__ x,
    const float* __restrict__ emb,
    const int*   __restrict__ ei,
    const int*   __restrict__ ew,
    float*       __restrict__ prop)
{
    int gid = blockIdx.x * blockDim.x + threadIdx.x;
    int e = gid >> 5;
    if (e >= N_EDGES) return;
    int d4 = (gid & 31) * 4;
    int src = ei[e];
    int dst = ei[N_EDGES + e];
    int w   = ew[e];
    float4 ev = *(const float4*)(emb + (size_t)w * D + d4);
    float4 xv = *(const float4*)(x + (size_t)src * D + d4);
    float* p = prop + (size_t)dst * D + d4;
    atomicAdd(p + 0, ev.x * xv.x);
    atomicAdd(p + 1, ev.y * xv.y);
    atomicAdd(p + 2, ev.z * xv.z);
    atomicAdd(p + 3, ev.w * xv.w);
}

__global__ __launch_bounds__(256) void mfma_gemm_fb(
    const float* __restrict__ x,
    float*       __restrict__ out,
    const unsigned short* __restrict__ Bh,
    const unsigned short* __restrict__ Bl,
    const float* __restrict__ bl_,
    const float* __restrict__ br_)
{
    __shared__ unsigned short Ah_s[128 * 40];
    __shared__ unsigned short Al_s[128 * 40];
    __shared__ unsigned short Bh_s[128 * 40];
    __shared__ unsigned short Bl_s[128 * 40];

    const int tid  = threadIdx.x;
    const int lane = tid & 63;
    const int wave = tid >> 6;
    const int row0 = blockIdx.x * 128;
    const int wr0 = (wave >> 1) * 64;
    const int wc0 = (wave & 1) * 64;
    const int lr  = lane & 15;
    const int lk8 = (lane >> 4) * 8;
    const int srow  = tid >> 1;
    const int skoff = (tid & 1) * 16;

    f32x4 acc[4][4];
#pragma unroll
    for (int i = 0; i < 4; i++)
#pragma unroll
        for (int j = 0; j < 4; j++)
            acc[i][j] = (f32x4){0.f, 0.f, 0.f, 0.f};

    for (int kc = 0; kc < 8; ++kc) {
        const int kbase = kc * 32;
        {
            const float* Asrc = (kbase < 128) ? x : out;
            const int acol = (kbase & 127) + skoff;
            const int grow = row0 + srow;
            float v[16];
            if (grow < N_NODES) {
                const float4* p = (const float4*)(Asrc + (size_t)grow * D + acol);
#pragma unroll
                for (int q = 0; q < 4; q++) {
                    float4 f = p[q];
                    v[q*4+0] = f.x; v[q*4+1] = f.y; v[q*4+2] = f.z; v[q*4+3] = f.w;
                }
            } else {
#pragma unroll
                for (int q = 0; q < 16; q++) v[q] = 0.f;
            }
            short8v h0, h1, l0, l1;
#pragma unroll
            for (int q = 0; q < 8; q++) {
                unsigned short h = f2bf(v[q]);
                h0[q] = (short)h;
                l0[q] = (short)f2bf(v[q] - bf2f(h));
            }
#pragma unroll
            for (int q = 0; q < 8; q++) {
                unsigned short h = f2bf(v[q + 8]);
                h1[q] = (short)h;
                l1[q] = (short)f2bf(v[q + 8] - bf2f(h));
            }
            *(short8v*)(Ah_s + srow * 40 + skoff)     = h0;
            *(short8v*)(Ah_s + srow * 40 + skoff + 8) = h1;
            *(short8v*)(Al_s + srow * 40 + skoff)     = l0;
            *(short8v*)(Al_s + srow * 40 + skoff + 8) = l1;
        }
        {
            const size_t boff = (size_t)srow * 256 + kbase + skoff;
            *(short8v*)(Bh_s + srow * 40 + skoff)     = *(const short8v*)(Bh + boff);
            *(short8v*)(Bh_s + srow * 40 + skoff + 8) = *(const short8v*)(Bh + boff + 8);
            *(short8v*)(Bl_s + srow * 40 + skoff)     = *(const short8v*)(Bl + boff);
            *(short8v*)(Bl_s + srow * 40 + skoff + 8) = *(const short8v*)(Bl + boff + 8);
        }
        __syncthreads();
        short8v afh[4], afl[4];
#pragma unroll
        for (int rt = 0; rt < 4; rt++) {
            int ar = wr0 + rt * 16 + lr;
            afh[rt] = *(const short8v*)(Ah_s + ar * 40 + lk8);
            afl[rt] = *(const short8v*)(Al_s + ar * 40 + lk8);
        }
#pragma unroll
        for (int ct = 0; ct < 4; ct++) {
            int bc = wc0 + ct * 16 + lr;
            short8v bfh = *(const short8v*)(Bh_s + bc * 40 + lk8);
            short8v bfl = *(const short8v*)(Bl_s + bc * 40 + lk8);
#pragma unroll
            for (int rt = 0; rt < 4; rt++)
                acc[rt][ct] = __builtin_amdgcn_mfma_f32_16x16x32_bf16(afh[rt], bfh, acc[rt][ct], 0, 0, 0);
#pragma unroll
            for (int rt = 0; rt < 4; rt++)
                acc[rt][ct] = __builtin_amdgcn_mfma_f32_16x16x32_bf16(afl[rt], bfh, acc[rt][ct], 0, 0, 0);
#pragma unroll
            for (int rt = 0; rt < 4; rt++)
                acc[rt][ct] = __builtin_amdgcn_mfma_f32_16x16x32_bf16(afh[rt], bfl, acc[rt][ct], 0, 0, 0);
        }
        __syncthreads();
    }

    const int drow = (lane >> 4) * 4;
#pragma unroll
    for (int ct = 0; ct < 4; ct++) {
        int col = wc0 + ct * 16 + lr;
        float bias = bl_[col] + br_[col];
#pragma unroll
        for (int rt = 0; rt < 4; rt++) {
#pragma unroll
            for (int r = 0; r < 4; r++) {
                int grow = row0 + wr0 + rt * 16 + drow + r;
                if (grow < N_NODES)
                    out[(size_t)grow * D + col] = acc[rt][ct][r] + bias;
            }
        }
    }
}

// ============================================================================
extern "C" void kernel_launch(void* const* d_in, const int* in_sizes, int n_in,
                              void* d_out, int out_size, void* d_ws, size_t ws_size,
                              hipStream_t stream) {
    const float* x    = (const float*)d_in[0];
    const float* emb  = (const float*)d_in[1];
    const float* W_l  = (const float*)d_in[2];
    const float* b_l  = (const float*)d_in[3];
    const float* W_r  = (const float*)d_in[4];
    const float* b_r  = (const float*)d_in[5];
    const int*   ei   = (const int*)d_in[6];
    const int*   ew   = (const int*)d_in[7];

    float* out = (float*)d_out;

    char* wsp = (char*)d_ws;
    unsigned short* Bh  = (unsigned short*)wsp; wsp += 128 * 256 * sizeof(unsigned short);
    unsigned short* Bl  = (unsigned short*)wsp; wsp += 128 * 256 * sizeof(unsigned short);
    unsigned short* xh  = (unsigned short*)wsp; wsp += (size_t)(N_NODES + 1) * D * sizeof(unsigned short);
    unsigned short* ph  = (unsigned short*)wsp; wsp += (size_t)N_NODES * D * sizeof(unsigned short);
    unsigned short* pl  = (unsigned short*)wsp; wsp += (size_t)N_NODES * D * sizeof(unsigned short);
    int*      counts    = (int*)wsp;     wsp += N_NODES * sizeof(int);
    int*      offs      = (int*)wsp;     wsp += (N_NODES + 1) * sizeof(int);
    int*      rank      = (int*)wsp;     wsp += N_EDGES * sizeof(int);
    unsigned* cursor    = (unsigned*)wsp; wsp += 4 * sizeof(unsigned);
    unsigned* packed    = (unsigned*)wsp; wsp += (size_t)PACK_CAP * sizeof(unsigned);
    size_t needed = (size_t)(wsp - (char*)d_ws);

    if (ws_size >= needed) {
        prep_kernel<<<128 + XPREP_BLOCKS + SCAN_BLOCKS + PFILL_BLOCKS + 1, 256, 0, stream>>>(
            W_l, W_r, Bh, Bl, x, xh, counts, packed, cursor);
        histrank_kernel<<<(N_EDGES + 255) / 256, 256, 0, stream>>>(ei, counts, rank);
        alloc_kernel<<<SCAN_BLOCKS, 256, 0, stream>>>(counts, cursor, offs);
        pack_kernel<<<(N_EDGES + 255) / 256, 256, 0, stream>>>(ei, ew, offs, rank, packed);
        aggregate_kernel<<<(N_NODES + 3) / 4, 256, 0, stream>>>(
            xh, emb, offs, counts, packed, ph, pl);
        mfma_gemm<<<(N_NODES + 127) / 128, 256, 0, stream>>>(
            x, ph, pl, out, Bh, Bl, b_l, b_r);
    } else {
        wprep_kernel<<<128, 256, 0, stream>>>(W_l, W_r, Bh, Bl);
        int n4 = N_NODES * D / 4;
        zero_kernel<<<(n4 + 255) / 256, 256, 0, stream>>>((float4*)out, n4);
        long long work = (long long)N_EDGES * 32;
        scatter_kernel<<<(int)((work + 255) / 256), 256, 0, stream>>>(x, emb, ei, ew, out);
        mfma_gemm_fb<<<(N_NODES + 127) / 128, 256, 0, stream>>>(x, out, Bh, Bl, b_l, b_r);
    }
}